// Round 9
// baseline (182.803 us; speedup 1.0000x reference)
//
#include <hip/hip_runtime.h>

#define NB 32
#define HH 512
#define WW 512
#define TAPS 9                        // outer 2 taps carry 3e-6 mass -> dropped, renormalized
#define RAD 4
#define TX 256                        // threads; each computes 2 adjacent px -> full 512-wide row
#define YB 16
#define NR (YB + 2*RAD)               // 24 input rows per strip
#define YSTRIPS (HH / YB)             // 32
#define NBLK (NB * YSTRIPS)           // 1024 blocks x 4 waves = 16 waves/CU
#define EW 260                        // even/odd array width (float4 cols)

// packed 2xfp32 FMA with wave-uniform tap in SGPR pair (frees VGPRs; 1 SGPR/VALU ok)
__device__ __forceinline__ float2 pk_fma_s(float2 g_sgpr, float2 b, float2 c) {
    float2 d;
    asm("v_pk_fma_f32 %0, %1, %2, %3" : "=v"(d) : "s"(g_sgpr), "v"(b), "v"(c));
    return d;
}

__global__ __launch_bounds__(TX, 4)   // cap 128 VGPR
void ssim_main(const float* __restrict__ pred,
               const float* __restrict__ targ,
               const float* __restrict__ win,
               float* __restrict__ partial)
{
    // [parity]: E[j] = col 2j-4, O[j] = col 2j-3; cols are {p,t,p*t,p^2+t^2}
    __shared__ float4 ldsE[2][EW], ldsO[2][EW];   // 16.6 KB

    const int tid = threadIdx.x;
    const int bid = blockIdx.x;
    const int ystrip = bid & (YSTRIPS - 1);
    const int img    = bid >> 5;
    const int y0 = ystrip * YB;

    // 9-tap renormalized 1D gaussian from the window (wave-uniform)
    float2 G[TAPS];
    {
        const float inv = rsqrtf(win[5*11 + 5]);
        float s = 0.f;
        float gr[TAPS];
        #pragma unroll
        for (int i = 0; i < TAPS; ++i) { gr[i] = win[5*11 + 1 + i] * inv; s += gr[i]; }
        const float rn = __fdividef(1.f, s);
        #pragma unroll
        for (int i = 0; i < TAPS; ++i) { const float v = gr[i] * rn; G[i] = make_float2(v, v); }
    }

    const float* __restrict__ pimg = pred + (size_t)img * (HH*WW);
    const float* __restrict__ timg = targ + (size_t)img * (HH*WW);

    const int xm = 2*tid - 4;            // main pair: cols xm, xm+1 (8B-aligned, valid iff tid>=2)
    // tail cols (threads 0..7): E[256+i] (x=508+2i) or O[256+(i-4)] (x=509+2(i-4))
    const int xt = (tid < 4) ? (508 + 2*tid) : (509 + 2*(tid - 4));

    // ring buffers: h-conv results, 9 rows x {mu,cs} x 2 px (static indices only)
    float2 rmu0[TAPS], rcs0[TAPS], rmu1[TAPS], rcs1[TAPS];

    float2 P, T;          // current row main pair (p,t at xm, xm+1)
    float  tp, tt;        // current row tail scalar
    float2 nP, nT; float ntp, ntt;

    auto fetch = [&](int r, float2& Pv, float2& Tv, float& tpv, float& ttv) {
        const int yin = y0 - RAD + r;
        const bool yok = (yin >= 0) & (yin < HH);   // wave-uniform
        Pv = make_float2(0.f, 0.f); Tv = make_float2(0.f, 0.f); tpv = 0.f; ttv = 0.f;
        if (yok) {
            const float* prow = pimg + yin * WW;
            const float* trow = timg + yin * WW;
            if (tid >= 2) {
                Pv = *reinterpret_cast<const float2*>(prow + xm);
                Tv = *reinterpret_cast<const float2*>(trow + xm);
            }
            if (tid < 8 && xt < WW) { tpv = prow[xt]; ttv = trow[xt]; }
        }
    };

    fetch(0, P, T, tp, tt);

    float acc = 0.f;
    const float C1 = 1.0e-4f, C2 = 9.0e-4f;

    #pragma unroll 1
    for (int rb = 0; rb < (NR + TAPS - 1) / TAPS; ++rb) {
        #pragma unroll
        for (int j = 0; j < TAPS; ++j) {
            const int r = rb * TAPS + j;     // ring slot = r % 9 = j (static)
            if (r < NR) {
                const int par = r & 1;
                // stage: E[tid] (x=2t-4), O[tid] (x=2t-3), + tails from threads 0..7
                ldsE[par][tid] = make_float4(P.x, T.x, P.x*T.x, fmaf(P.x, P.x, T.x*T.x));
                ldsO[par][tid] = make_float4(P.y, T.y, P.y*T.y, fmaf(P.y, P.y, T.y*T.y));
                if (tid < 4)
                    ldsE[par][256 + tid]   = make_float4(tp, tt, tp*tt, fmaf(tp, tp, tt*tt));
                else if (tid < 8)
                    ldsO[par][252 + tid]   = make_float4(tp, tt, tp*tt, fmaf(tp, tp, tt*tt));
                // prefetch next row over the barrier
                if (r + 1 < NR) fetch(r + 1, nP, nT, ntp, ntt);
                __syncthreads();

                // h-conv for out px x=2*tid (0) and x=2*tid+1 (1): 10 b128 reads, 36 pk-FMA
                {
                    float2 smu0 = make_float2(0.f,0.f), scs0 = smu0, smu1 = smu0, scs1 = smu0;
                    #pragma unroll
                    for (int q = 0; q < 5; ++q) {
                        const float4 e = ldsE[par][tid + q];    // x = 2tid-4+2q
                        const float2 emu = make_float2(e.x, e.y), ecs = make_float2(e.z, e.w);
                        smu0 = pk_fma_s(G[2*q], emu, smu0);
                        scs0 = pk_fma_s(G[2*q], ecs, scs0);
                        if (q >= 1) {
                            smu1 = pk_fma_s(G[2*q - 1], emu, smu1);
                            scs1 = pk_fma_s(G[2*q - 1], ecs, scs1);
                        }
                        const float4 o = ldsO[par][tid + q];    // x = 2tid-3+2q
                        const float2 omu = make_float2(o.x, o.y), ocs = make_float2(o.z, o.w);
                        smu1 = pk_fma_s(G[2*q], omu, smu1);
                        scs1 = pk_fma_s(G[2*q], ocs, scs1);
                        if (q <= 3) {
                            smu0 = pk_fma_s(G[2*q + 1], omu, smu0);
                            scs0 = pk_fma_s(G[2*q + 1], ocs, scs0);
                        }
                    }
                    rmu0[j] = smu0; rcs0[j] = scs0; rmu1[j] = smu1; rcs1[j] = scs1;
                }

                // vertical conv + SSIM for output row y0 + r - 8, both px
                if (r >= 2*RAD) {
                    float2 mu0 = make_float2(0.f,0.f), cs0 = mu0, mu1 = mu0, cs1 = mu0;
                    #pragma unroll
                    for (int k = 0; k < TAPS; ++k) {
                        const int s = (j + 1 + k) % TAPS;   // static after unroll
                        mu0 = pk_fma_s(G[k], rmu0[s], mu0);
                        cs0 = pk_fma_s(G[k], rcs0[s], cs0);
                        mu1 = pk_fma_s(G[k], rmu1[s], mu1);
                        cs1 = pk_fma_s(G[k], rcs1[s], cs1);
                    }
                    #pragma unroll
                    for (int px = 0; px < 2; ++px) {
                        const float2 mu = px ? mu1 : mu0;
                        const float2 cs = px ? cs1 : cs0;
                        const float m11 = mu.x * mu.x;
                        const float m22 = mu.y * mu.y;
                        const float m12 = mu.x * mu.y;
                        const float msum = m11 + m22;
                        const float num = (2.f*m12 + C1) * (2.f*(cs.x - m12) + C2);
                        const float den = (msum + C1) * ((cs.y - msum) + C2);
                        acc += __fdividef(num, den);
                    }
                }
                P = nP; T = nT; tp = ntp; tt = ntt;
            }
        }
    }

    // block reduction -> one partial per block (deterministic, no atomics)
    #pragma unroll
    for (int off = 32; off > 0; off >>= 1)
        acc += __shfl_down(acc, off, 64);
    __shared__ float red[4];
    if ((tid & 63) == 0) red[tid >> 6] = acc;
    __syncthreads();
    if (tid == 0) partial[bid] = red[0] + red[1] + red[2] + red[3];
}

__global__ void ssim_final(const float* __restrict__ partial, float* __restrict__ out)
{
    const int tid = threadIdx.x;
    float v = 0.f;
    #pragma unroll
    for (int i = 0; i < NBLK / 256; ++i)
        v += partial[tid + 256 * i];
    #pragma unroll
    for (int off = 32; off > 0; off >>= 1)
        v += __shfl_down(v, off, 64);
    __shared__ float red[4];
    if ((tid & 63) == 0) red[tid >> 6] = v;
    __syncthreads();
    if (tid == 0)
        out[0] = 1.f - (red[0] + red[1] + red[2] + red[3]) / (float)(NB * HH * WW);
}

extern "C" void kernel_launch(void* const* d_in, const int* in_sizes, int n_in,
                              void* d_out, int out_size, void* d_ws, size_t ws_size,
                              hipStream_t stream) {
    const float* pred = (const float*)d_in[0];
    const float* targ = (const float*)d_in[1];
    const float* win  = (const float*)d_in[2];
    float* out = (float*)d_out;
    float* partial = (float*)d_ws;   // NBLK floats = 4 KB

    ssim_main<<<NBLK, TX, 0, stream>>>(pred, targ, win, partial);
    ssim_final<<<1, 256, 0, stream>>>(partial, out);
}